// Round 8
// baseline (1026.393 us; speedup 1.0000x reference)
//
#include <hip/hip_runtime.h>
#include <hip/hip_fp16.h>

// NodeModel: agg = segment_sum(x[row], col); h = concat(x, agg); out = MLP(h).
//
// Path A (two-stage sort, fp16 value materialization, ~320 MB ws):
//   1) counting-sort edges by row-bucket (row>>12, 245 cursors = proven
//      write-combining-safe); payload (col<<12)|row_local (exact u32, N<2^20).
//   2) seg_hist + scans: col-bucket layout of the value stream.
//   3) valscatter: per row-bucket, x-tile (48KB) in LDS; emit 8-byte entries
//      {fp16 x0,x1,x2, u16 col_local} at col-bucket cursor positions.
//      208 MB stream -> fits the 256 MB L3 (round-6's float4 = 416 MB didn't).
//   4) val_agg: stream the L3-resident segment, LDS-atomic accumulate,
//      fused node MLP epilogue. Zero global random accesses anywhere.
// Path B: round-3 col-sort + gather agg (measured 728us).
// Path C: global atomicAdd + separate MLP.

#define SH    12
#define TILE  4096            // nodes per bucket (48 KB LDS tile/acc)
#define MAXNB 256             // cb must fit in (p>>24)
#define NBLK  512             // edge chunks for hist/scatter
#define THR   1024

// ---------------- generic sort kernels ----------------

__global__ __launch_bounds__(THR) void hist_kernel(
    const int* __restrict__ key, int* __restrict__ hist,
    int nb, int chunk, int n_edges)
{
    __shared__ int lh[MAXNB];
    const int t = threadIdx.x, b = blockIdx.x;
    for (int k = t; k < nb; k += THR) lh[k] = 0;
    __syncthreads();

    long long s = (long long)b * chunk;
    long long e = s + chunk; if (e > n_edges) e = n_edges;
    if (s < e) {
        const int n = (int)(e - s);
        const int n4 = n >> 2;
        const int4* __restrict__ k4p = reinterpret_cast<const int4*>(key + s);
        for (int i = t; i < n4; i += THR) {
            int4 c = k4p[i];
            atomicAdd(&lh[(unsigned)c.x >> SH], 1);
            atomicAdd(&lh[(unsigned)c.y >> SH], 1);
            atomicAdd(&lh[(unsigned)c.z >> SH], 1);
            atomicAdd(&lh[(unsigned)c.w >> SH], 1);
        }
        for (int i = (n4 << 2) + t; i < n; i += THR)
            atomicAdd(&lh[(unsigned)key[s + i] >> SH], 1);
    }
    __syncthreads();
    for (int k = t; k < nb; k += THR) hist[(size_t)b * nb + k] = lh[k];
}

__global__ __launch_bounds__(NBLK) void scan_blocks_kernel(
    int* __restrict__ hist, int* __restrict__ keyTotal, int nb)
{
    __shared__ int sd[NBLK];
    const int t = threadIdx.x, k = blockIdx.x;
    const int v = hist[(size_t)t * nb + k];
    sd[t] = v; __syncthreads();
#pragma unroll
    for (int off = 1; off < NBLK; off <<= 1) {
        int a = (t >= off) ? sd[t - off] : 0;
        __syncthreads();
        sd[t] += a;
        __syncthreads();
    }
    hist[(size_t)t * nb + k] = sd[t] - v;
    if (t == NBLK - 1) keyTotal[k] = sd[t];
}

__global__ __launch_bounds__(1024) void scan_keys_kernel(
    const int* __restrict__ keyTotal, int* __restrict__ keyStart, int nb)
{
    __shared__ int sd[1024];
    const int t = threadIdx.x;
    const int v = (t < nb) ? keyTotal[t] : 0;
    sd[t] = v; __syncthreads();
#pragma unroll
    for (int off = 1; off < 1024; off <<= 1) {
        int a = (t >= off) ? sd[t - off] : 0;
        __syncthreads();
        sd[t] += a;
        __syncthreads();
    }
    if (t < nb) keyStart[t] = sd[t] - v;
    if (t == 0) keyStart[nb] = sd[1023];
}

// sort by key>>SH, payload (other<<SH)|(key&(TILE-1))
__global__ __launch_bounds__(THR) void scatter_kernel(
    const int* __restrict__ key, const int* __restrict__ other,
    const int* __restrict__ hist, const int* __restrict__ keyStart,
    unsigned* __restrict__ packed, int nb, int chunk, int n_edges)
{
    __shared__ int lc[MAXNB];
    const int t = threadIdx.x, b = blockIdx.x;
    for (int k = t; k < nb; k += THR)
        lc[k] = keyStart[k] + hist[(size_t)b * nb + k];
    __syncthreads();

    long long s = (long long)b * chunk;
    long long e = s + chunk; if (e > n_edges) e = n_edges;
    if (s < e) {
        const int n = (int)(e - s);
        const int n4 = n >> 2;
        const int4* __restrict__ k4p = reinterpret_cast<const int4*>(key + s);
        const int4* __restrict__ o4p = reinterpret_cast<const int4*>(other + s);
        for (int i = t; i < n4; i += THR) {
            int4 c = k4p[i];
            int4 r = o4p[i];
            int p;
            p = atomicAdd(&lc[(unsigned)c.x >> SH], 1);
            packed[p] = ((unsigned)r.x << SH) | ((unsigned)c.x & (TILE - 1));
            p = atomicAdd(&lc[(unsigned)c.y >> SH], 1);
            packed[p] = ((unsigned)r.y << SH) | ((unsigned)c.y & (TILE - 1));
            p = atomicAdd(&lc[(unsigned)c.z >> SH], 1);
            packed[p] = ((unsigned)r.z << SH) | ((unsigned)c.z & (TILE - 1));
            p = atomicAdd(&lc[(unsigned)c.w >> SH], 1);
            packed[p] = ((unsigned)r.w << SH) | ((unsigned)c.w & (TILE - 1));
        }
        for (int i = (n4 << 2) + t; i < n; i += THR) {
            int c = key[s + i], r = other[s + i];
            int p = atomicAdd(&lc[(unsigned)c >> SH], 1);
            packed[p] = ((unsigned)r << SH) | ((unsigned)c & (TILE - 1));
        }
    }
}

// ---------------- Path A kernels ----------------

// per row-bucket: histogram of col-bucket (p>>24) over its segment
__global__ __launch_bounds__(THR) void seg_hist_kernel(
    const unsigned* __restrict__ packed, const int* __restrict__ keyStart1,
    int* __restrict__ hist2, int nb)
{
    __shared__ int lh[MAXNB];
    const int t = threadIdx.x, rb = blockIdx.x;
    for (int k = t; k < nb; k += THR) lh[k] = 0;
    __syncthreads();

    const int s = keyStart1[rb], e = keyStart1[rb + 1];
    int s4 = (s + 3) & ~3; if (s4 > e) s4 = e;
    const int e4 = s4 + ((e - s4) & ~3);
    const uint4* __restrict__ p4p = reinterpret_cast<const uint4*>(packed);

    for (int i = s + t; i < s4; i += THR) atomicAdd(&lh[packed[i] >> 24], 1);
    for (int i = e4 + t; i < e; i += THR) atomicAdd(&lh[packed[i] >> 24], 1);
    for (int i = (s4 >> 2) + t; i < (e4 >> 2); i += THR) {
        uint4 p = p4p[i];
        atomicAdd(&lh[p.x >> 24], 1);
        atomicAdd(&lh[p.y >> 24], 1);
        atomicAdd(&lh[p.z >> 24], 1);
        atomicAdd(&lh[p.w >> 24], 1);
    }
    __syncthreads();
    for (int k = t; k < nb; k += THR) hist2[(size_t)rb * nb + k] = lh[k];
}

// per col-bucket cb: exclusive scan of hist2[rb][cb] along rb; cbTotal
__global__ __launch_bounds__(256) void scan_rb_kernel(
    int* __restrict__ hist2, int* __restrict__ cbTotal, int nb)
{
    __shared__ int sd[256];
    const int t = threadIdx.x, cb = blockIdx.x;
    const int v = (t < nb) ? hist2[(size_t)t * nb + cb] : 0;
    sd[t] = v; __syncthreads();
#pragma unroll
    for (int off = 1; off < 256; off <<= 1) {
        int a = (t >= off) ? sd[t - off] : 0;
        __syncthreads();
        sd[t] += a;
        __syncthreads();
    }
    if (t < nb) hist2[(size_t)t * nb + cb] = sd[t] - v;
    if (t == 255) cbTotal[cb] = sd[255];
}

// per row-bucket: x-tile in LDS; emit {fp16 x0,x1,x2, u16 col_local}
// at col-bucket cursor positions (245 cursors, runs ~3.5 KB).
__global__ __launch_bounds__(THR) void valscatter_kernel(
    const unsigned* __restrict__ packed, const float* __restrict__ x,
    const int* __restrict__ keyStart1, const int* __restrict__ hist2,
    const int* __restrict__ colStart, ushort4* __restrict__ val,
    int nb, int n_nodes)
{
    __shared__ float tile[TILE * 3];   // 48 KB
    __shared__ int cur[MAXNB];
    const int t = threadIdx.x, rb = blockIdx.x;

    for (int k = t; k < nb; k += THR)
        cur[k] = colStart[k] + hist2[(size_t)rb * nb + k];

    const long long base = (long long)rb << SH;
    long long liml = (long long)n_nodes - base;
    const int lim = (int)(liml > TILE ? TILE : (liml > 0 ? liml : 0));
    for (int f = t; f < lim * 3; f += THR) tile[f] = x[base * 3 + f];
    __syncthreads();

    const int s = keyStart1[rb], e = keyStart1[rb + 1];
    int s4 = (s + 3) & ~3; if (s4 > e) s4 = e;
    const int e4 = s4 + ((e - s4) & ~3);
    const uint4* __restrict__ p4p = reinterpret_cast<const uint4*>(packed);

    auto emit = [&](unsigned p) {
        const int rl = (int)(p & (TILE - 1)) * 3;
        ushort4 v;
        v.x = __half_as_ushort(__float2half_rn(tile[rl]));
        v.y = __half_as_ushort(__float2half_rn(tile[rl + 1]));
        v.z = __half_as_ushort(__float2half_rn(tile[rl + 2]));
        v.w = (unsigned short)((p >> SH) & (TILE - 1));
        const int q = atomicAdd(&cur[p >> 24], 1);
        val[q] = v;
    };

    for (int i = s + t; i < s4; i += THR) emit(packed[i]);
    for (int i = e4 + t; i < e; i += THR) emit(packed[i]);
    for (int i = (s4 >> 2) + t; i < (e4 >> 2); i += THR) {
        uint4 p = p4p[i];
        emit(p.x); emit(p.y); emit(p.z); emit(p.w);
    }
}

// per col-bucket: stream the L3-resident 8B entries, LDS-atomic acc,
// fused node MLP epilogue.
__global__ __launch_bounds__(THR) void val_agg_mlp_kernel(
    const ushort4* __restrict__ val, const int* __restrict__ colStart,
    const float* __restrict__ x,
    const float* __restrict__ W1, const float* __restrict__ b1,
    const float* __restrict__ W2, const float* __restrict__ b2,
    const float* __restrict__ W3, const float* __restrict__ b3,
    float* __restrict__ out, int n_nodes)
{
    __shared__ float acc[TILE * 3];   // 48 KB
    __shared__ float sW1[96], sb1[16], sW2[256], sb2[16], sW3[48], sb3[3];
    const int t = threadIdx.x, cb = blockIdx.x;

    if (t < 96)  sW1[t] = W1[t];
    if (t < 16)  sb1[t] = b1[t];
    if (t < 256) sW2[t] = W2[t];
    if (t >= 256 && t < 272) sb2[t - 256] = b2[t - 256];
    if (t >= 272 && t < 320) sW3[t - 272] = W3[t - 272];
    if (t >= 320 && t < 323) sb3[t - 320] = b3[t - 320];
    for (int f = t; f < TILE * 3; f += THR) acc[f] = 0.0f;
    __syncthreads();

    const int s = colStart[cb], e = colStart[cb + 1];

    auto add1 = [&](ushort4 v) {
        const float f0 = __half2float(__ushort_as_half(v.x));
        const float f1 = __half2float(__ushort_as_half(v.y));
        const float f2 = __half2float(__ushort_as_half(v.z));
        const int j = (int)v.w * 3;
        atomicAdd(&acc[j + 0], f0);
        atomicAdd(&acc[j + 1], f1);
        atomicAdd(&acc[j + 2], f2);
    };

    int i = s + t;
    for (; i + 3 * THR < e; i += 4 * THR) {
        ushort4 v0 = val[i];
        ushort4 v1 = val[i + THR];
        ushort4 v2 = val[i + 2 * THR];
        ushort4 v3 = val[i + 3 * THR];
        add1(v0); add1(v1); add1(v2); add1(v3);
    }
    for (; i < e; i += THR) add1(val[i]);
    __syncthreads();

    const long long base = (long long)cb << SH;
    long long lim = (long long)n_nodes - base;
    if (lim > TILE) lim = TILE;
    if (lim <= 0) return;

    for (int j = t; j < (int)lim; j += THR) {
        const long long node = base + j;
        float in6[6];
        in6[0] = x[3 * node + 0];
        in6[1] = x[3 * node + 1];
        in6[2] = x[3 * node + 2];
        in6[3] = acc[3 * j + 0];
        in6[4] = acc[3 * j + 1];
        in6[5] = acc[3 * j + 2];

        float h1[16];
#pragma unroll
        for (int q = 0; q < 16; ++q) {
            float sv = sb1[q];
#pragma unroll
            for (int r = 0; r < 6; ++r) sv = fmaf(in6[r], sW1[r * 16 + q], sv);
            h1[q] = fmaxf(sv, 0.0f);
        }
        float h2[16];
#pragma unroll
        for (int q = 0; q < 16; ++q) {
            float sv = sb2[q];
#pragma unroll
            for (int r = 0; r < 16; ++r) sv = fmaf(h1[r], sW2[r * 16 + q], sv);
            h2[q] = fmaxf(sv, 0.0f);
        }
        float o0 = sb3[0], o1 = sb3[1], o2 = sb3[2];
#pragma unroll
        for (int q = 0; q < 16; ++q) {
            o0 = fmaf(h2[q], sW3[q * 3 + 0], o0);
            o1 = fmaf(h2[q], sW3[q * 3 + 1], o1);
            o2 = fmaf(h2[q], sW3[q * 3 + 2], o2);
        }
        out[3 * node + 0] = o0;
        out[3 * node + 1] = o1;
        out[3 * node + 2] = o2;
    }
}

// ---------------- Path B: col-sort + gather agg (round-3, 728us) ----------

__global__ __launch_bounds__(THR) void bucket_agg_mlp_kernel(
    const unsigned* __restrict__ packed, const float* __restrict__ x,
    const int* __restrict__ keyStart,
    const float* __restrict__ W1, const float* __restrict__ b1,
    const float* __restrict__ W2, const float* __restrict__ b2,
    const float* __restrict__ W3, const float* __restrict__ b3,
    float* __restrict__ out, int n_nodes)
{
    __shared__ float acc[TILE * 3];
    __shared__ float sW1[96], sb1[16], sW2[256], sb2[16], sW3[48], sb3[3];
    const int t = threadIdx.x, k = blockIdx.x;

    if (t < 96)  sW1[t] = W1[t];
    if (t < 16)  sb1[t] = b1[t];
    if (t < 256) sW2[t] = W2[t];
    if (t >= 256 && t < 272) sb2[t - 256] = b2[t - 256];
    if (t >= 272 && t < 320) sW3[t - 272] = W3[t - 272];
    if (t >= 320 && t < 323) sb3[t - 320] = b3[t - 320];
    for (int f = t; f < TILE * 3; f += THR) acc[f] = 0.0f;
    __syncthreads();

    const int s = keyStart[k];
    const int e = keyStart[k + 1];
    int i = s + t;
    for (; i + 3 * THR < e; i += 4 * THR) {
        unsigned p0 = packed[i];
        unsigned p1 = packed[i + THR];
        unsigned p2 = packed[i + 2 * THR];
        unsigned p3 = packed[i + 3 * THR];
        const float* xs0 = x + 3ll * (p0 >> SH);
        const float* xs1 = x + 3ll * (p1 >> SH);
        const float* xs2 = x + 3ll * (p2 >> SH);
        const float* xs3 = x + 3ll * (p3 >> SH);
        float a0 = xs0[0], b0 = xs0[1], c0 = xs0[2];
        float a1 = xs1[0], b1v = xs1[1], c1 = xs1[2];
        float a2 = xs2[0], b2v = xs2[1], c2 = xs2[2];
        float a3 = xs3[0], b3v = xs3[1], c3 = xs3[2];
        int j0 = (int)(p0 & (TILE - 1)) * 3;
        int j1 = (int)(p1 & (TILE - 1)) * 3;
        int j2 = (int)(p2 & (TILE - 1)) * 3;
        int j3 = (int)(p3 & (TILE - 1)) * 3;
        atomicAdd(&acc[j0 + 0], a0); atomicAdd(&acc[j0 + 1], b0);  atomicAdd(&acc[j0 + 2], c0);
        atomicAdd(&acc[j1 + 0], a1); atomicAdd(&acc[j1 + 1], b1v); atomicAdd(&acc[j1 + 2], c1);
        atomicAdd(&acc[j2 + 0], a2); atomicAdd(&acc[j2 + 1], b2v); atomicAdd(&acc[j2 + 2], c2);
        atomicAdd(&acc[j3 + 0], a3); atomicAdd(&acc[j3 + 1], b3v); atomicAdd(&acc[j3 + 2], c3);
    }
    for (; i < e; i += THR) {
        const unsigned p = packed[i];
        const float* __restrict__ xs = x + 3ll * (p >> SH);
        const int j = (int)(p & (TILE - 1)) * 3;
        atomicAdd(&acc[j + 0], xs[0]);
        atomicAdd(&acc[j + 1], xs[1]);
        atomicAdd(&acc[j + 2], xs[2]);
    }
    __syncthreads();

    const long long base = (long long)k << SH;
    long long lim = (long long)n_nodes - base;
    if (lim > TILE) lim = TILE;
    if (lim <= 0) return;

    for (int j = t; j < (int)lim; j += THR) {
        const long long node = base + j;
        float in6[6];
        in6[0] = x[3 * node + 0];
        in6[1] = x[3 * node + 1];
        in6[2] = x[3 * node + 2];
        in6[3] = acc[3 * j + 0];
        in6[4] = acc[3 * j + 1];
        in6[5] = acc[3 * j + 2];

        float h1[16];
#pragma unroll
        for (int q = 0; q < 16; ++q) {
            float sv = sb1[q];
#pragma unroll
            for (int r = 0; r < 6; ++r) sv = fmaf(in6[r], sW1[r * 16 + q], sv);
            h1[q] = fmaxf(sv, 0.0f);
        }
        float h2[16];
#pragma unroll
        for (int q = 0; q < 16; ++q) {
            float sv = sb2[q];
#pragma unroll
            for (int r = 0; r < 16; ++r) sv = fmaf(h1[r], sW2[r * 16 + q], sv);
            h2[q] = fmaxf(sv, 0.0f);
        }
        float o0 = sb3[0], o1 = sb3[1], o2 = sb3[2];
#pragma unroll
        for (int q = 0; q < 16; ++q) {
            o0 = fmaf(h2[q], sW3[q * 3 + 0], o0);
            o1 = fmaf(h2[q], sW3[q * 3 + 1], o1);
            o2 = fmaf(h2[q], sW3[q * 3 + 2], o2);
        }
        out[3 * node + 0] = o0;
        out[3 * node + 1] = o1;
        out[3 * node + 2] = o2;
    }
}

// ---------------- Path C ----------------

__global__ __launch_bounds__(256) void edge_scatter_kernel(
    const int* __restrict__ rows, const int* __restrict__ cols,
    const float* __restrict__ x, float* __restrict__ agg, int n_edges)
{
    const long long tid = (long long)blockIdx.x * blockDim.x + threadIdx.x;
    const long long stride = (long long)gridDim.x * blockDim.x;
    for (long long i = tid; i < n_edges; i += stride) {
        int r = rows[i], c = cols[i];
        const float* xs = x + 3ll * r; float* a = agg + 3ll * c;
        atomicAdd(a + 0, xs[0]); atomicAdd(a + 1, xs[1]); atomicAdd(a + 2, xs[2]);
    }
}

__global__ __launch_bounds__(256) void node_mlp_kernel(
    const float* __restrict__ x,
    const float* __restrict__ W1, const float* __restrict__ b1,
    const float* __restrict__ W2, const float* __restrict__ b2,
    const float* __restrict__ W3, const float* __restrict__ b3,
    float* __restrict__ out, int n_nodes)
{
    __shared__ float sW1[96], sb1[16], sW2[256], sb2[16], sW3[48], sb3[3];
    const int t = threadIdx.x;
    if (t < 96)  sW1[t] = W1[t];
    if (t < 16)  sb1[t] = b1[t];
    sW2[t] = W2[t];
    if (t < 16)  sb2[t] = b2[t];
    if (t < 48)  sW3[t] = W3[t];
    if (t < 3)   sb3[t] = b3[t];
    __syncthreads();

    const int i = blockIdx.x * 256 + t;
    if (i >= n_nodes) return;

    float in6[6];
    in6[0] = x[3 * i + 0];
    in6[1] = x[3 * i + 1];
    in6[2] = x[3 * i + 2];
    in6[3] = out[3 * i + 0];
    in6[4] = out[3 * i + 1];
    in6[5] = out[3 * i + 2];

    float h1[16];
#pragma unroll
    for (int j = 0; j < 16; ++j) {
        float s = sb1[j];
#pragma unroll
        for (int k = 0; k < 6; ++k) s = fmaf(in6[k], sW1[k * 16 + j], s);
        h1[j] = fmaxf(s, 0.0f);
    }
    float h2[16];
#pragma unroll
    for (int j = 0; j < 16; ++j) {
        float s = sb2[j];
#pragma unroll
        for (int k = 0; k < 16; ++k) s = fmaf(h1[k], sW2[k * 16 + j], s);
        h2[j] = fmaxf(s, 0.0f);
    }
    float o[3];
#pragma unroll
    for (int c = 0; c < 3; ++c) {
        float s = sb3[c];
#pragma unroll
        for (int j = 0; j < 16; ++j) s = fmaf(h2[j], sW3[j * 3 + c], s);
        o[c] = s;
    }
    out[3 * i + 0] = o[0];
    out[3 * i + 1] = o[1];
    out[3 * i + 2] = o[2];
}

extern "C" void kernel_launch(void* const* d_in, const int* in_sizes, int n_in,
                              void* d_out, int out_size, void* d_ws, size_t ws_size,
                              hipStream_t stream) {
    const float* x   = (const float*)d_in[0];
    const int*   ei  = (const int*)d_in[1];   // [2, E] int32
    const float* W1  = (const float*)d_in[5];
    const float* b1  = (const float*)d_in[6];
    const float* W2  = (const float*)d_in[7];
    const float* b2  = (const float*)d_in[8];
    const float* W3  = (const float*)d_in[9];
    const float* b3  = (const float*)d_in[10];

    const int n_nodes = in_sizes[0] / 3;
    const int n_edges = in_sizes[1] / 2;
    const int* rows = ei;            // edge_index[0]
    const int* cols = ei + n_edges;  // edge_index[1]
    float* out = (float*)d_out;

    const int nb = (n_nodes + TILE - 1) >> SH;

    int chunk = (n_edges + NBLK - 1) / NBLK;
    chunk = (chunk + 3) & ~3;        // keep per-block int4 loads 16B-aligned

    // Path A layout: packed[E] u32 | val[E] ushort4(8B) | hist1[NBLK*nb]
    //   | keyTotal[nb] | keyStart1[nb+1] | hist2[nb*nb] | cbTotal[nb] | colStart[nb+1]
    const size_t off_packed = 0;
    const size_t off_val    = off_packed + (size_t)n_edges * 4;
    const size_t off_hist1  = off_val + (size_t)n_edges * 8;
    const size_t off_kt     = off_hist1 + (size_t)NBLK * nb * 4;
    const size_t off_ks1    = off_kt + (size_t)nb * 4;
    const size_t off_hist2  = off_ks1 + (size_t)(nb + 1) * 4;
    const size_t off_cbt    = off_hist2 + (size_t)nb * nb * 4;
    const size_t off_cs     = off_cbt + (size_t)nb * 4;
    const size_t needA      = off_cs + (size_t)(nb + 1) * 4;

    const size_t needB = (size_t)n_edges * 4 + (size_t)NBLK * nb * 4
                       + (size_t)nb * 4 + (size_t)(nb + 1) * 4;
    const bool okA = (ws_size >= needA) && (nb <= MAXNB) && (n_nodes <= (1 << 20));
    const bool okB = (ws_size >= needB) && (nb <= MAXNB) && (n_nodes <= (1 << 20));

    if (okA) {
        unsigned* packed    = (unsigned*)((char*)d_ws + off_packed);
        ushort4*  val       = (ushort4*)((char*)d_ws + off_val);
        int*      hist1     = (int*)((char*)d_ws + off_hist1);
        int*      keyTotal  = (int*)((char*)d_ws + off_kt);
        int*      keyStart1 = (int*)((char*)d_ws + off_ks1);
        int*      hist2     = (int*)((char*)d_ws + off_hist2);
        int*      cbTotal   = (int*)((char*)d_ws + off_cbt);
        int*      colStart  = (int*)((char*)d_ws + off_cs);

        // sort 1: by row-bucket, payload (col<<12)|row_local
        hist_kernel<<<NBLK, THR, 0, stream>>>(rows, hist1, nb, chunk, n_edges);
        scan_blocks_kernel<<<nb, NBLK, 0, stream>>>(hist1, keyTotal, nb);
        scan_keys_kernel<<<1, 1024, 0, stream>>>(keyTotal, keyStart1, nb);
        scatter_kernel<<<NBLK, THR, 0, stream>>>(rows, cols, hist1, keyStart1,
                                                 packed, nb, chunk, n_edges);
        // col-bucket layout of the value stream
        seg_hist_kernel<<<nb, THR, 0, stream>>>(packed, keyStart1, hist2, nb);
        scan_rb_kernel<<<nb, 256, 0, stream>>>(hist2, cbTotal, nb);
        scan_keys_kernel<<<1, 1024, 0, stream>>>(cbTotal, colStart, nb);
        // materialize fp16 values (LDS x-tile; 8B entries -> L3-resident)
        valscatter_kernel<<<nb, THR, 0, stream>>>(packed, x, keyStart1, hist2,
                                                  colStart, val, nb, n_nodes);
        // aggregate + fused MLP
        val_agg_mlp_kernel<<<nb, THR, 0, stream>>>(val, colStart, x,
                                                   W1, b1, W2, b2, W3, b3,
                                                   out, n_nodes);
    } else if (okB) {
        unsigned* packed = (unsigned*)d_ws;
        int* hist1       = (int*)(packed + n_edges);
        int* keyTotal    = hist1 + (size_t)NBLK * nb;
        int* keyStart    = keyTotal + nb;

        hist_kernel<<<NBLK, THR, 0, stream>>>(cols, hist1, nb, chunk, n_edges);
        scan_blocks_kernel<<<nb, NBLK, 0, stream>>>(hist1, keyTotal, nb);
        scan_keys_kernel<<<1, 1024, 0, stream>>>(keyTotal, keyStart, nb);
        scatter_kernel<<<NBLK, THR, 0, stream>>>(cols, rows, hist1, keyStart,
                                                 packed, nb, chunk, n_edges);
        bucket_agg_mlp_kernel<<<nb, THR, 0, stream>>>(
            packed, x, keyStart, W1, b1, W2, b2, W3, b3, out, n_nodes);
    } else {
        hipMemsetAsync(d_out, 0, (size_t)out_size * sizeof(float), stream);
        edge_scatter_kernel<<<8192, 256, 0, stream>>>(rows, cols, x, out, n_edges);
        node_mlp_kernel<<<(n_nodes + 255) / 256, 256, 0, stream>>>(
            x, W1, b1, W2, b2, W3, b3, out, n_nodes);
    }
}